// Round 3
// baseline (330.032 us; speedup 1.0000x reference)
//
#include <hip/hip_runtime.h>

// x:(B,T,2P) f32, resolution:(B,T,2) f32, origin:(B,T,2) f32
// -> out:(B,T,H,W,P) f32 one-hot raster grid.
#define BB 32
#define TT 10
#define PP 25
#define HH 100
#define WW 100

// Per-bt slice: H*W*P = 250,000 floats = 62,500 float4 (divisible by 4, base 16B-aligned).
#define SLICE4 62500
#define CHUNKS 10                  // chunks per bt slice
#define CHUNK4 (SLICE4 / CHUNKS)   // 6,250 float4 per chunk

// Native vector type: __builtin_nontemporal_store requires a vector of
// scalar types, not HIP's float4 struct.
typedef float floatx4 __attribute__((ext_vector_type(4)));

__global__ void raster_fused_kernel(const float* __restrict__ x,
                                    const float* __restrict__ res,
                                    const float* __restrict__ org,
                                    float* __restrict__ out) {
    const int bt    = blockIdx.y;   // 0..319
    const int chunk = blockIdx.x;   // 0..CHUNKS-1
    const int t     = threadIdx.x;

    // Each block computes its bt's 25 point targets (flat float offset within
    // the bt slice), -1 if out of bounds. Redundant across chunks but trivial.
    __shared__ int tgt[PP];
    if (t < PP) {
        const float px = x[bt * (2 * PP) + 2 * t];
        const float py = x[bt * (2 * PP) + 2 * t + 1];
        const float r0 = res[bt * 2 + 0];   // row uses resolution[...,0]
        const float r1 = res[bt * 2 + 1];   // col uses resolution[...,1]
        const float o0 = org[bt * 2 + 0];
        const float o1 = org[bt * 2 + 1];
        // .astype(int32) truncates toward zero, same as C cast.
        const int row = (int)(py / r0 + o0);
        const int col = (int)(px / r1 + o1);
        tgt[t] = (row >= 0 && row < HH && col >= 0 && col < WW)
                     ? ((row * WW + col) * PP + t)
                     : -1;
    }
    __syncthreads();

    // Zero-fill this block's chunk: coalesced float4 streaming stores.
    floatx4* dst = (floatx4*)out + (size_t)bt * SLICE4 + (size_t)chunk * CHUNK4;
    const floatx4 z = (floatx4)(0.0f);
    for (int i = t; i < CHUNK4; i += blockDim.x) {
        __builtin_nontemporal_store(z, dst + i);
    }

    // Barrier drains vmcnt(0) -> zero stores complete before the 1-writes.
    __syncthreads();

    if (t < PP) {
        const int g  = tgt[t];
        const int lo = chunk * CHUNK4 * 4;
        const int hi = lo + CHUNK4 * 4;
        if (g >= lo && g < hi) {
            out[(size_t)bt * SLICE4 * 4 + (size_t)g] = 1.0f;
        }
    }
}

extern "C" void kernel_launch(void* const* d_in, const int* in_sizes, int n_in,
                              void* d_out, int out_size, void* d_ws, size_t ws_size,
                              hipStream_t stream) {
    const float* x          = (const float*)d_in[0];
    const float* resolution = (const float*)d_in[1];
    const float* origin     = (const float*)d_in[2];
    float* out = (float*)d_out;

    dim3 grid(CHUNKS, BB * TT);   // 3200 blocks, ~12 per CU
    raster_fused_kernel<<<grid, 256, 0, stream>>>(x, resolution, origin, out);
}

// Round 4
// 324.824 us; speedup vs baseline: 1.0160x; 1.0160x over previous
//
#include <hip/hip_runtime.h>

// x:(B,T,2P) f32, resolution:(B,T,2) f32, origin:(B,T,2) f32
// -> out:(B,T,H,W,P) f32 one-hot raster grid.
#define BB 32
#define TT 10
#define PP 25
#define HH 100
#define WW 100

// Per-bt slice: H*W*P = 250,000 floats = 62,500 float4 (divisible by 4, base 16B-aligned).
#define SLICE4 62500
#define CHUNKS 10                  // chunks per bt slice
#define CHUNK4 (SLICE4 / CHUNKS)   // 6,250 float4 per chunk

typedef float floatx4 __attribute__((ext_vector_type(4)));

__global__ void raster_fused_kernel(const float* __restrict__ x,
                                    const float* __restrict__ res,
                                    const float* __restrict__ org,
                                    float* __restrict__ out) {
    const int bt    = blockIdx.y;   // 0..319
    const int chunk = blockIdx.x;   // 0..CHUNKS-1
    const int t     = threadIdx.x;

    // Each block computes its bt's 25 point targets (flat float offset within
    // the bt slice), -1 if out of bounds. Redundant across chunks but trivial.
    __shared__ int tgt[PP];
    if (t < PP) {
        const float px = x[bt * (2 * PP) + 2 * t];
        const float py = x[bt * (2 * PP) + 2 * t + 1];
        const float r0 = res[bt * 2 + 0];   // row uses resolution[...,0]
        const float r1 = res[bt * 2 + 1];   // col uses resolution[...,1]
        const float o0 = org[bt * 2 + 0];
        const float o1 = org[bt * 2 + 1];
        // .astype(int32) truncates toward zero, same as C cast.
        const int row = (int)(py / r0 + o0);
        const int col = (int)(px / r1 + o1);
        tgt[t] = (row >= 0 && row < HH && col >= 0 && col < WW)
                     ? ((row * WW + col) * PP + t)
                     : -1;
    }
    __syncthreads();

    // Zero-fill this block's chunk: coalesced float4 streaming stores.
    // Plain (cached) stores — nontemporal hint measured ~2.5x slower on gfx950
    // for this pattern; full-line dirty evictions hit ~6.2 TB/s.
    floatx4* dst = (floatx4*)out + (size_t)bt * SLICE4 + (size_t)chunk * CHUNK4;
    const floatx4 z = (floatx4)(0.0f);
    for (int i = t; i < CHUNK4; i += blockDim.x) {
        dst[i] = z;
    }

    // Barrier drains vmcnt(0) -> zero stores complete before the 1-writes.
    __syncthreads();

    if (t < PP) {
        const int g  = tgt[t];
        const int lo = chunk * CHUNK4 * 4;
        const int hi = lo + CHUNK4 * 4;
        if (g >= lo && g < hi) {
            out[(size_t)bt * SLICE4 * 4 + (size_t)g] = 1.0f;
        }
    }
}

extern "C" void kernel_launch(void* const* d_in, const int* in_sizes, int n_in,
                              void* d_out, int out_size, void* d_ws, size_t ws_size,
                              hipStream_t stream) {
    const float* x          = (const float*)d_in[0];
    const float* resolution = (const float*)d_in[1];
    const float* origin     = (const float*)d_in[2];
    float* out = (float*)d_out;

    dim3 grid(CHUNKS, BB * TT);   // 3200 blocks, ~12 per CU
    raster_fused_kernel<<<grid, 256, 0, stream>>>(x, resolution, origin, out);
}

// Round 5
// 313.153 us; speedup vs baseline: 1.0539x; 1.0373x over previous
//
#include <hip/hip_runtime.h>

// x:(B,T,2P) f32, resolution:(B,T,2) f32, origin:(B,T,2) f32
// -> out:(B,T,H,W,P) f32 one-hot raster grid.
// Structure: driver memset (6.2 TB/s fill of the 320 MB output) + tiny
// 8000-thread scatter of 1.0s. Measured best (R1 = 311 us vs fused = 325 us):
// the hand-rolled fused fill only reached ~4 TB/s, losing more than the
// saved launch gap. ~246 us of the timed window is harness poison fills
// (1.28 GB @ ~211 us visible in rocprof) that we cannot touch.
#define BB 32
#define TT 10
#define PP 25
#define HH 100
#define WW 100

__global__ void raster_scatter_kernel(const float* __restrict__ x,
                                      const float* __restrict__ resolution,
                                      const float* __restrict__ origin,
                                      float* __restrict__ out) {
    int tid = blockIdx.x * blockDim.x + threadIdx.x;
    const int N = BB * TT * PP;  // 8000
    if (tid >= N) return;

    int p  = tid % PP;
    int bt = tid / PP;           // fused (b,t) index, 0..319

    // points layout: x[bt][2p] = x-coord, x[bt][2p+1] = y-coord
    const float px = x[bt * (2 * PP) + 2 * p];
    const float py = x[bt * (2 * PP) + 2 * p + 1];
    const float r0 = resolution[bt * 2 + 0];  // row uses res[...,0]
    const float r1 = resolution[bt * 2 + 1];  // col uses res[...,1]
    const float o0 = origin[bt * 2 + 0];
    const float o1 = origin[bt * 2 + 1];

    // jnp .astype(int32) truncates toward zero, same as C cast.
    int row = (int)(py / r0 + o0);
    int col = (int)(px / r1 + o1);

    if (row >= 0 && row < HH && col >= 0 && col < WW) {
        size_t idx = (((size_t)bt * HH + (size_t)row) * WW + (size_t)col) * PP + (size_t)p;
        out[idx] = 1.0f;
    }
}

extern "C" void kernel_launch(void* const* d_in, const int* in_sizes, int n_in,
                              void* d_out, int out_size, void* d_ws, size_t ws_size,
                              hipStream_t stream) {
    const float* x          = (const float*)d_in[0];
    const float* resolution = (const float*)d_in[1];
    const float* origin     = (const float*)d_in[2];
    float* out = (float*)d_out;

    // Zero the 320 MB output (harness poisons it with 0xAA before each call).
    hipMemsetAsync(out, 0, (size_t)out_size * sizeof(float), stream);

    const int N = BB * TT * PP;  // 8000 points
    raster_scatter_kernel<<<(N + 255) / 256, 256, 0, stream>>>(x, resolution, origin, out);
}